// Round 1
// baseline (145.801 us; speedup 1.0000x reference)
//
#include <hip/hip_runtime.h>
#include <hip/hip_bf16.h>

#define IMG_SIZE 256
#define NPIX (IMG_SIZE * IMG_SIZE)
#define KSEL 5
#define BS 8
#define LL 64
#define NTHREADS 256

// Insert key into ascending sorted 5-list (lexicographic (dist,idx) via packed u64).
__device__ __forceinline__ void insert5(unsigned long long* loc, unsigned long long key) {
    if (key < loc[4]) {
        int j = 4;
        while (j > 0 && loc[j - 1] > key) { loc[j] = loc[j - 1]; --j; }
        loc[j] = key;
    }
}

// Merge two ascending 5-lists, keep smallest 5 into a.
__device__ __forceinline__ void merge5(unsigned long long* a, const unsigned long long* b) {
    unsigned long long out[KSEL];
    int ia = 0, ib = 0;
    #pragma unroll
    for (int j = 0; j < KSEL; ++j) {
        // ia+ib == j < 5, so both indices are <= 4 here: safe.
        out[j] = (a[ia] <= b[ib]) ? a[ia++] : b[ib++];
    }
    #pragma unroll
    for (int j = 0; j < KSEL; ++j) a[j] = out[j];
}

__device__ __forceinline__ unsigned long long
pix_key(float r0, float r1, float r2, float c0, float c1, float c2, int pix) {
    // Match numpy f32: diff = ref - pooled; sum over 3 channels as ((d0^2+d1^2)+d2^2),
    // no FMA contraction.
    float d0 = __fsub_rn(r0, c0);
    float d1 = __fsub_rn(r1, c1);
    float d2 = __fsub_rn(r2, c2);
    float s = __fadd_rn(__fadd_rn(__fmul_rn(d0, d0), __fmul_rn(d1, d1)), __fmul_rn(d2, d2));
    // s >= 0 always (sum of squares) -> uint bit order == float order.
    return ((unsigned long long)__float_as_uint(s) << 32) | (unsigned int)pix;
}

// One block per (b,l): compute pooled color, scan image b for top-5 closest pixels.
__global__ __launch_bounds__(NTHREADS)
void topk_kernel(const float* __restrict__ preds,
                 const float* __restrict__ imgs,
                 int* __restrict__ topk) {
    const int bid = blockIdx.x;          // b*LL + l
    const int b = bid >> 6;
    const int l = bid & 63;
    const int t = threadIdx.x;

    // Scrambled pooled indexing: flat i = l*bs + b; position from preds[i//L, i%L].
    const int i = l * BS + b;
    const int pb = i >> 6;
    const int pl = i & 63;
    const float px = preds[pb * (LL * 8) + pl * 8 + 0];
    const float py = preds[pb * (LL * 8) + pl * 8 + 1];

    // grid_sample nearest, align_corners=False, zeros padding.
    const float cx = __fsub_rn(__fmul_rn(px, 256.0f), 0.5f);
    const float cy = __fsub_rn(__fmul_rn(py, 256.0f), 0.5f);
    const int ix = (int)rintf(cx);       // rintf = round half to even (matches jnp.rint)
    const int iy = (int)rintf(cy);
    const bool valid = (ix >= 0) && (ix < IMG_SIZE) && (iy >= 0) && (iy < IMG_SIZE);
    const int ixc = min(max(ix, 0), IMG_SIZE - 1);
    const int iyc = min(max(iy, 0), IMG_SIZE - 1);
    const float vmul = valid ? 1.0f : 0.0f;

    const float* imgb = imgs + (size_t)b * 3 * NPIX;
    const float c0 = imgb[0 * NPIX + iyc * IMG_SIZE + ixc] * vmul;
    const float c1 = imgb[1 * NPIX + iyc * IMG_SIZE + ixc] * vmul;
    const float c2 = imgb[2 * NPIX + iyc * IMG_SIZE + ixc] * vmul;

    const float4* p0 = (const float4*)(imgb + 0 * NPIX);
    const float4* p1 = (const float4*)(imgb + 1 * NPIX);
    const float4* p2 = (const float4*)(imgb + 2 * NPIX);

    unsigned long long loc[KSEL];
    #pragma unroll
    for (int j = 0; j < KSEL; ++j) loc[j] = 0xFFFFFFFFFFFFFFFFULL;

    // 65536 pixels / 4 per float4 = 16384 vectors; 64 iterations of 256 threads.
    for (int v = t; v < NPIX / 4; v += NTHREADS) {
        float4 r0 = p0[v];
        float4 r1 = p1[v];
        float4 r2 = p2[v];
        int base = v * 4;
        insert5(loc, pix_key(r0.x, r1.x, r2.x, c0, c1, c2, base + 0));
        insert5(loc, pix_key(r0.y, r1.y, r2.y, c0, c1, c2, base + 1));
        insert5(loc, pix_key(r0.z, r1.z, r2.z, c0, c1, c2, base + 2));
        insert5(loc, pix_key(r0.w, r1.w, r2.w, c0, c1, c2, base + 3));
    }

    __shared__ unsigned long long sk[NTHREADS * KSEL];
    #pragma unroll
    for (int j = 0; j < KSEL; ++j) sk[t * KSEL + j] = loc[j];
    __syncthreads();

    for (int s = NTHREADS / 2; s > 0; s >>= 1) {
        if (t < s) {
            unsigned long long a[KSEL], bb[KSEL];
            #pragma unroll
            for (int j = 0; j < KSEL; ++j) { a[j] = sk[t * KSEL + j]; bb[j] = sk[(t + s) * KSEL + j]; }
            merge5(a, bb);
            #pragma unroll
            for (int j = 0; j < KSEL; ++j) sk[t * KSEL + j] = a[j];
        }
        __syncthreads();
    }

    if (t < KSEL) {
        topk[bid * KSEL + t] = (int)(sk[t] & 0xFFFFFFFFULL);
    }
}

// Epilogue: roll along L, argmin over K of positional dist (== loss element), mean.
__global__ __launch_bounds__(NTHREADS)
void finalize_kernel(const float* __restrict__ preds,
                     const int* __restrict__ topk,
                     float* __restrict__ out) {
    const int t = threadIdx.x;
    float acc = 0.0f;

    for (int pair = t; pair < BS * LL; pair += NTHREADS) {
        const int b = pair >> 6;
        const int l = pair & 63;
        if (l == 0) continue;  // loss uses l >= 1 only
        const float px = preds[b * (LL * 8) + l * 8 + 0];
        const float py = preds[b * (LL * 8) + l * 8 + 1];
        // tgt_down[:, l] = tgt[:, l-1]
        const int* id = &topk[(b * LL + (l - 1)) * KSEL];
        float best = 3.4028235e38f;
        #pragma unroll
        for (int k = 0; k < KSEL; ++k) {
            const int ixk = id[k];
            const float tx = (float)(ixk & 255) * (1.0f / 256.0f);   // exact /256
            const float ty = (float)(ixk >> 8) * (1.0f / 256.0f);
            const float dx = __fsub_rn(px, tx);
            const float dy = __fsub_rn(py, ty);
            const float dist = __fadd_rn(__fmul_rn(dx, dx), __fmul_rn(dy, dy));
            if (dist < best) best = dist;  // strict less -> first-min tie semantics
        }
        acc += best;
    }

    __shared__ float red[NTHREADS];
    red[t] = acc;
    __syncthreads();
    for (int s = NTHREADS / 2; s > 0; s >>= 1) {
        if (t < s) red[t] += red[t + s];
        __syncthreads();
    }
    if (t == 0) {
        out[0] = red[0] / (float)(BS * (LL - 1));
    }
}

extern "C" void kernel_launch(void* const* d_in, const int* in_sizes, int n_in,
                              void* d_out, int out_size, void* d_ws, size_t ws_size,
                              hipStream_t stream) {
    const float* preds = (const float*)d_in[0];   // (8, 64, 8) f32
    const float* imgs  = (const float*)d_in[1];   // (8, 3, 256, 256) f32
    float* out = (float*)d_out;                   // scalar f32
    int* topk = (int*)d_ws;                       // 512 * 5 ints

    topk_kernel<<<dim3(BS * LL), dim3(NTHREADS), 0, stream>>>(preds, imgs, topk);
    finalize_kernel<<<dim3(1), dim3(NTHREADS), 0, stream>>>(preds, topk, out);
}

// Round 2
// 100.813 us; speedup vs baseline: 1.4463x; 1.4463x over previous
//
#include <hip/hip_runtime.h>
#include <hip/hip_bf16.h>

#define IMG_SIZE 256
#define NPIX (IMG_SIZE * IMG_SIZE)
#define KSEL 5
#define BS 8
#define LL 64
#define LUSED 63          // row l=63's top-k is discarded by the roll — never compute it
#define NTHREADS 256
#define SPLIT 4           // blocks per (b,l) row
#define CHUNK (NPIX / SPLIT)      // 16384 pixels per block

typedef unsigned long long ull;

// Branchless sorted-insert: loc[] ascending; bubble key in, evict the max.
// Static indices only -> stays in VGPRs; no divergence.
__device__ __forceinline__ void sort_insert(ull loc[KSEL], ull key) {
    #pragma unroll
    for (int j = 0; j < KSEL; ++j) {
        const ull a = loc[j];
        const bool lt = key < a;
        loc[j] = lt ? key : a;
        key    = lt ? a : key;
    }
}

// Merge two ascending 5-lists, keep smallest 5 into a (branchless enough; used
// only in the small LDS tree).
__device__ __forceinline__ void merge5(ull* a, const ull* b) {
    ull out[KSEL];
    int ia = 0, ib = 0;
    #pragma unroll
    for (int j = 0; j < KSEL; ++j) {
        const ull va = a[ia], vb = b[ib];
        const bool ta = va <= vb;
        out[j] = ta ? va : vb;
        ia += ta ? 1 : 0;
        ib += ta ? 0 : 1;
    }
    #pragma unroll
    for (int j = 0; j < KSEL; ++j) a[j] = out[j];
}

__device__ __forceinline__ ull
pix_key(float r0, float r1, float r2, float c0, float c1, float c2, int pix) {
    // Match numpy f32 exactly: no FMA contraction, ((d0^2+d1^2)+d2^2).
    float d0 = __fsub_rn(r0, c0);
    float d1 = __fsub_rn(r1, c1);
    float d2 = __fsub_rn(r2, c2);
    float s = __fadd_rn(__fadd_rn(__fmul_rn(d0, d0), __fmul_rn(d1, d1)), __fmul_rn(d2, d2));
    // s >= 0 (sum of squares) -> uint bit order == float order; low bits = pixel
    // index gives jax top_k's lower-index-first tie-break.
    return ((ull)__float_as_uint(s) << 32) | (unsigned int)pix;
}

// One block per (b,l,split): scan CHUNK pixels of image b, emit sorted top-5 keys.
__global__ __launch_bounds__(NTHREADS)
void topk_kernel(const float* __restrict__ preds,
                 const float* __restrict__ imgs,
                 ull* __restrict__ keys_out) {
    const int blk = blockIdx.x;
    const int split = blk & (SPLIT - 1);
    const int row = blk / SPLIT;         // 0 .. BS*LUSED-1
    const int b = row / LUSED;
    const int l = row % LUSED;
    const int bid = b * LL + l;          // storage row (l < 63)
    const int t = threadIdx.x;

    // Scrambled pooled indexing: flat i = l*bs + b; position from preds[i//L, i%L].
    const int i = l * BS + b;
    const int pb = i >> 6;
    const int pl = i & 63;
    const float px = preds[pb * (LL * 8) + pl * 8 + 0];
    const float py = preds[pb * (LL * 8) + pl * 8 + 1];

    // grid_sample nearest, align_corners=False, zeros padding.
    const float cx = __fsub_rn(__fmul_rn(px, 256.0f), 0.5f);
    const float cy = __fsub_rn(__fmul_rn(py, 256.0f), 0.5f);
    const int ix = (int)rintf(cx);       // round half to even == jnp.rint
    const int iy = (int)rintf(cy);
    const bool valid = (ix >= 0) && (ix < IMG_SIZE) && (iy >= 0) && (iy < IMG_SIZE);
    const int ixc = min(max(ix, 0), IMG_SIZE - 1);
    const int iyc = min(max(iy, 0), IMG_SIZE - 1);
    const float vmul = valid ? 1.0f : 0.0f;

    const float* imgb = imgs + (size_t)b * 3 * NPIX;
    const float c0 = imgb[0 * NPIX + iyc * IMG_SIZE + ixc] * vmul;
    const float c1 = imgb[1 * NPIX + iyc * IMG_SIZE + ixc] * vmul;
    const float c2 = imgb[2 * NPIX + iyc * IMG_SIZE + ixc] * vmul;

    const float4* p0 = (const float4*)(imgb + 0 * NPIX);
    const float4* p1 = (const float4*)(imgb + 1 * NPIX);
    const float4* p2 = (const float4*)(imgb + 2 * NPIX);

    ull loc[KSEL];
    #pragma unroll
    for (int j = 0; j < KSEL; ++j) loc[j] = 0xFFFFFFFFFFFFFFFFULL;

    // CHUNK/4 = 4096 float4s; 16 iterations of 256 threads.
    const int v0 = split * (CHUNK / 4);
    #pragma unroll 2
    for (int it = 0; it < CHUNK / 4 / NTHREADS; ++it) {
        const int v = v0 + it * NTHREADS + t;
        float4 r0 = p0[v];
        float4 r1 = p1[v];
        float4 r2 = p2[v];
        const int base = v * 4;
        sort_insert(loc, pix_key(r0.x, r1.x, r2.x, c0, c1, c2, base + 0));
        sort_insert(loc, pix_key(r0.y, r1.y, r2.y, c0, c1, c2, base + 1));
        sort_insert(loc, pix_key(r0.z, r1.z, r2.z, c0, c1, c2, base + 2));
        sort_insert(loc, pix_key(r0.w, r1.w, r2.w, c0, c1, c2, base + 3));
    }

    __shared__ ull sk[NTHREADS * KSEL];
    #pragma unroll
    for (int j = 0; j < KSEL; ++j) sk[t * KSEL + j] = loc[j];
    __syncthreads();

    for (int s = NTHREADS / 2; s > 0; s >>= 1) {
        if (t < s) {
            ull a[KSEL], bb[KSEL];
            #pragma unroll
            for (int j = 0; j < KSEL; ++j) { a[j] = sk[t * KSEL + j]; bb[j] = sk[(t + s) * KSEL + j]; }
            merge5(a, bb);
            #pragma unroll
            for (int j = 0; j < KSEL; ++j) sk[t * KSEL + j] = a[j];
        }
        __syncthreads();
    }

    if (t < KSEL) {
        keys_out[((size_t)bid * SPLIT + split) * KSEL + t] = sk[t];
    }
}

// Epilogue: merge the SPLIT partial top-5s per row, roll along L, min positional
// distance over the 5 selected pixels (== loss element), mean.
__global__ __launch_bounds__(NTHREADS)
void finalize_kernel(const float* __restrict__ preds,
                     const ull* __restrict__ keys,
                     float* __restrict__ out) {
    const int t = threadIdx.x;
    float acc = 0.0f;

    for (int p = t; p < BS * LUSED; p += NTHREADS) {
        const int b = p / LUSED;
        const int l = p % LUSED + 1;              // loss rows: l = 1..63
        const float px = preds[b * (LL * 8) + l * 8 + 0];
        const float py = preds[b * (LL * 8) + l * 8 + 1];

        // tgt_down[:, l] = tgt[:, l-1]: merge the SPLIT sorted 5-lists of row l-1.
        const int srow = b * LL + (l - 1);
        ull loc[KSEL];
        #pragma unroll
        for (int j = 0; j < KSEL; ++j) loc[j] = 0xFFFFFFFFFFFFFFFFULL;
        #pragma unroll
        for (int s = 0; s < SPLIT; ++s) {
            #pragma unroll
            for (int k = 0; k < KSEL; ++k) {
                sort_insert(loc, keys[((size_t)srow * SPLIT + s) * KSEL + k]);
            }
        }

        float best = 3.4028235e38f;
        #pragma unroll
        for (int k = 0; k < KSEL; ++k) {
            const int ixk = (int)(loc[k] & 0xFFFFFFFFULL);
            const float tx = (float)(ixk & 255) * (1.0f / 256.0f);   // exact /256
            const float ty = (float)(ixk >> 8) * (1.0f / 256.0f);
            const float dx = __fsub_rn(px, tx);
            const float dy = __fsub_rn(py, ty);
            const float dist = __fadd_rn(__fmul_rn(dx, dx), __fmul_rn(dy, dy));
            best = dist < best ? dist : best;
        }
        acc += best;
    }

    __shared__ float red[NTHREADS];
    red[t] = acc;
    __syncthreads();
    for (int s = NTHREADS / 2; s > 0; s >>= 1) {
        if (t < s) red[t] += red[t + s];
        __syncthreads();
    }
    if (t == 0) {
        out[0] = red[0] / (float)(BS * (LL - 1));
    }
}

extern "C" void kernel_launch(void* const* d_in, const int* in_sizes, int n_in,
                              void* d_out, int out_size, void* d_ws, size_t ws_size,
                              hipStream_t stream) {
    const float* preds = (const float*)d_in[0];   // (8, 64, 8) f32
    const float* imgs  = (const float*)d_in[1];   // (8, 3, 256, 256) f32
    float* out = (float*)d_out;                   // scalar f32
    ull* keys = (ull*)d_ws;                       // 512 * SPLIT * 5 u64 = 80 KB

    topk_kernel<<<dim3(BS * LUSED * SPLIT), dim3(NTHREADS), 0, stream>>>(preds, imgs, keys);
    finalize_kernel<<<dim3(1), dim3(NTHREADS), 0, stream>>>(preds, keys, out);
}